// Round 8
// baseline (425.650 us; speedup 1.0000x reference)
//
#include <hip/hip_runtime.h>

// ---------------------------------------------------------------------------
// TimeSeriesGCN — bf16 MFMA pipeline, batch-as-M GEMMs on position-major slabs.
// prep_edges:  edge_index -> dense bf16 Ahat[96][96]
// trans16:     src -> xt[96][8192][16] (bf16 transpose only)
// agg_mm<16>:  xt -> xa = Ahat @ xt            (dense-GEMM aggregation)
// gcn12:       xa(16ch) -> hw2[96][8192][32]
// agg_mm<32>:  hw2 -> h2 = relu(Ahat @ hw2 + b2)
// conv1/2/3:   LDS-free direct-fragment GEMMs (global->reg->MFMA, no K barriers)
// fc1_splitk:  c3 -> fp32 partials (6-way split-K, LDS-free)
// fc1_reduce:  partials -> feat (fp32 d_out) + fr (bf16 relu)
// cls1/cls2:   same template
// ---------------------------------------------------------------------------

typedef __attribute__((ext_vector_type(8))) short short8v;
typedef __attribute__((ext_vector_type(4))) float floatx4;

#define N_NODE 96
#define E_TOT  864
#define BATCH  8192ull

// ws layout, ushort elements
#define R0_OFF   0ull
#define R1_OFF   25165824ull
#define FR_OFF   50331648ull
#define R2_OFF   51380224ull
#define WT_OFF   52428800ull
#define W1N_OFF  (WT_OFF + 0)
#define W2N_OFF  (WT_OFF + 2048)
#define WC1_OFF  (WT_OFF + 4096)
#define WC2_OFF  (WT_OFF + 18432)
#define WC3_OFF  (WT_OFF + 59392)
#define WF1_OFF  (WT_OFF + 157696)
#define WL1_OFF  (WT_OFF + 550912)
#define WL2_OFF  (WT_OFF + 567296)
#define AH_OFF   (WT_OFF + 600064)   // dense Ahat bf16 [96][96]

__device__ __forceinline__ unsigned short f2b(float f) {
    unsigned int u = __builtin_bit_cast(unsigned int, f);
    u += 0x7fffu + ((u >> 16) & 1u);
    return (unsigned short)(u >> 16);
}
__device__ __forceinline__ float b2f(unsigned short h) {
    unsigned int u = ((unsigned int)h) << 16;
    return __builtin_bit_cast(float, u);
}

// ---------------------------------------------------------------------------
__global__ void prep_edges(const int* __restrict__ eidx, unsigned short* __restrict__ adense) {
    __shared__ int rowv[E_TOT];
    __shared__ int colv[E_TOT];
    __shared__ int degi[N_NODE];
    __shared__ float dinv[N_NODE];
    __shared__ float ad[96 * 96];
    const int tid = threadIdx.x;
    for (int e = tid; e < E_TOT; e += 256) {
        int r, c;
        if (e < 768) { r = eidx[e]; c = eidx[768 + e]; }
        else         { r = e - 768; c = r; }
        rowv[e] = r; colv[e] = c;
    }
    for (int n = tid; n < N_NODE; n += 256) degi[n] = 0;
    for (int i = tid; i < 9216; i += 256) ad[i] = 0.f;
    __syncthreads();
    for (int e = tid; e < E_TOT; e += 256) atomicAdd(&degi[rowv[e]], 1);
    __syncthreads();
    for (int n = tid; n < N_NODE; n += 256)
        dinv[n] = rsqrtf(fmaxf((float)degi[n], 1e-12f));
    __syncthreads();
    for (int e = tid; e < E_TOT; e += 256)
        atomicAdd(&ad[rowv[e] * 96 + colv[e]], dinv[rowv[e]] * dinv[colv[e]]);
    __syncthreads();
    for (int i = tid; i < 9216; i += 256) adense[i] = f2b(ad[i]);
}

// ---------------------------------------------------------------------------
__global__ void prep_weights(const float* __restrict__ g1w, const float* __restrict__ g2w,
                             const float* __restrict__ w1, const float* __restrict__ w2,
                             const float* __restrict__ w3, const float* __restrict__ f1,
                             const float* __restrict__ l1, const float* __restrict__ l2,
                             unsigned short* __restrict__ wt) {
    long idx = (long)blockIdx.x * 256 + threadIdx.x;
    if (idx >= 600064) return;
    float v;
    if (idx < 2048) {
        int o = idx >> 5, c = idx & 31;
        v = (c < 16) ? g1w[c * 64 + o] : 0.f;
    } else if (idx < 4096) {
        long j = idx - 2048; int g = j >> 6, c = j & 63;
        v = g2w[c * 32 + g];
    } else if (idx < 18432) {
        long j = idx - 4096; int o = j / 224, m = j % 224, t = m >> 5, c = m & 31;
        v = w1[o * 224 + c * 7 + t];
    } else if (idx < 59392) {
        long j = idx - 18432; int o = j / 320, m = j % 320, t = m >> 6, c = m & 63;
        v = w2[o * 320 + c * 5 + t];
    } else if (idx < 157696) {
        long j = idx - 59392; int o = j / 384, m = j % 384, t = m >> 7, c = m & 127;
        v = w3[o * 384 + c * 3 + t];
    } else if (idx < 550912) {
        long j = idx - 157696; int f = j / 3072, m = j % 3072, t = m >> 8, o = m & 255;
        v = f1[(o * 12 + t) * 128 + f];
    } else if (idx < 567296) {
        long j = idx - 550912; int f2 = j >> 7, ff = j & 127;
        v = l1[ff * 128 + f2];
    } else {
        long j = idx - 567296; int n = j >> 7, f = j & 127;
        v = (n < 210) ? l2[f * 210 + n] : 0.f;
    }
    wt[idx] = f2b(v);
}

// ---------------------------------------------------------------------------
__launch_bounds__(256)
__global__ void trans16(const float* __restrict__ src, unsigned short* __restrict__ xt) {
    __shared__ __align__(16) float xs[8 * 1544];
    const int tid = threadIdx.x;
    const int b0 = blockIdx.x * 8;
    for (int u = tid; u < 3072; u += 256) {
        int bl = u / 384, j = u % 384;
        *(float4*)&xs[bl * 1544 + j * 4] =
            *(const float4*)&src[((size_t)(b0 + bl)) * 1536 + j * 4];
    }
    __syncthreads();
    for (int u = tid; u < 768; u += 256) {
        int n = u >> 3, bl = u & 7;
        const float* base = &xs[bl * 1544 + n];
        unsigned int d[8];
#pragma unroll
        for (int c2 = 0; c2 < 8; c2++)
            d[c2] = (unsigned int)f2b(base[(2 * c2) * 96]) |
                    ((unsigned int)f2b(base[(2 * c2 + 1) * 96]) << 16);
        unsigned int* o = (unsigned int*)(xt + ((size_t)n * BATCH + b0 + bl) * 16);
        *(uint4*)&o[0] = make_uint4(d[0], d[1], d[2], d[3]);
        *(uint4*)&o[4] = make_uint4(d[4], d[5], d[6], d[7]);
    }
}

// ---------------------------------------------------------------------------
template<int CH, bool RELU>
__launch_bounds__(256)
__global__ void agg_mm(const unsigned short* __restrict__ in,
                       const unsigned short* __restrict__ adense,
                       const float* __restrict__ bias,
                       unsigned short* __restrict__ outp) {
    const size_t NCOL = 8192ull * CH;
    __shared__ __align__(16) unsigned short Al[96 * 104];
    __shared__ __align__(16) unsigned short Bs[96 * 264];
    const int tid = threadIdx.x;
    const size_t c0 = (size_t)blockIdx.x * 256;
    const int w = tid >> 6, lane = tid & 63, quad = lane >> 4, m16 = lane & 15;

    for (int u = tid; u < 1152; u += 256) {
        int r = u / 12, q = u % 12;
        *(short8v*)&Al[r * 104 + q * 8] = *(const short8v*)&adense[r * 96 + q * 8];
    }
    for (int u = tid; u < 3072; u += 256) {
        int r = u >> 5, q = u & 31;
        *(uint4*)&Bs[r * 264 + q * 8] = *(const uint4*)&in[(size_t)r * NCOL + c0 + q * 8];
    }
    __syncthreads();

    floatx4 acc[6][4] = {};
    const int nb = w * 64;
#pragma unroll
    for (int kk = 0; kk < 96; kk += 32) {
        short8v bfr[4];
#pragma unroll
        for (int fn = 0; fn < 4; fn++) {
            const int col = nb + fn * 16 + m16;
#pragma unroll
            for (int j = 0; j < 8; j++)
                bfr[fn][j] = (short)Bs[(kk + quad * 8 + j) * 264 + col];
        }
#pragma unroll
        for (int fm = 0; fm < 6; fm++) {
            short8v afr = *(short8v*)&Al[(fm * 16 + m16) * 104 + kk + quad * 8];
#pragma unroll
            for (int fn = 0; fn < 4; fn++)
                acc[fm][fn] = __builtin_amdgcn_mfma_f32_16x16x32_bf16(afr, bfr[fn], acc[fm][fn], 0, 0, 0);
        }
    }

#pragma unroll
    for (int fm = 0; fm < 6; fm++) {
#pragma unroll
        for (int fn = 0; fn < 4; fn++) {
            const int col = nb + fn * 16 + m16;
            float bv = 0.f;
            if constexpr (RELU) bv = bias[col & (CH - 1)];
#pragma unroll
            for (int r = 0; r < 4; r++) {
                int node = fm * 16 + quad * 4 + r;
                float v = acc[fm][fn][r];
                if constexpr (RELU) v = fmaxf(v + bv, 0.f);
                outp[(size_t)node * NCOL + c0 + col] = f2b(v);
            }
        }
    }
}

// ---------------------------------------------------------------------------
__launch_bounds__(256)
__global__ void gcn12(const unsigned short* __restrict__ xa,
                      const unsigned short* __restrict__ w1n,
                      const unsigned short* __restrict__ w2n,
                      const float* __restrict__ b1, unsigned short* __restrict__ hw2) {
    __shared__ __align__(16) unsigned short As[128 * 40];
    __shared__ __align__(16) unsigned short B1s[64 * 40];
    __shared__ __align__(16) unsigned short H1s[128 * 72];
    __shared__ __align__(16) unsigned short B2s[32 * 72];
    const int tid = threadIdx.x;
    const size_t b0 = blockIdx.x * 128;
    const int l = blockIdx.z;
    const int w = tid >> 6, lane = tid & 63, quad = lane >> 4, m16 = lane & 15;

    short8v zz = {0, 0, 0, 0, 0, 0, 0, 0};
    for (int u = tid; u < 512; u += 256) {
        int r = u >> 2, cc = u & 3;
        *(short8v*)&As[r * 40 + cc * 8] = (cc < 2)
            ? *(const short8v*)&xa[((size_t)l * BATCH + b0 + r) * 16 + cc * 8]
            : zz;
    }
    for (int u = tid; u < 256; u += 256) {
        int r = u >> 2, cc = u & 3;
        *(short8v*)&B1s[r * 40 + cc * 8] = *(const short8v*)&w1n[r * 32 + cc * 8];
    }
    for (int u = tid; u < 256; u += 256) {
        int r = u >> 3, cc = u & 7;
        *(short8v*)&B2s[r * 72 + cc * 8] = *(const short8v*)&w2n[r * 64 + cc * 8];
    }
    __syncthreads();

    {
        const int wm = w >> 1, wq = w & 1;
        const int mbase = wm * 64, nbase = wq * 32;
        floatx4 acc[4][2] = {};
#pragma unroll
        for (int fn = 0; fn < 2; fn++) {
            short8v bfr = *(short8v*)&B1s[(nbase + fn * 16 + m16) * 40 + quad * 8];
#pragma unroll
            for (int fm = 0; fm < 4; fm++) {
                short8v afr = *(short8v*)&As[(mbase + fm * 16 + m16) * 40 + quad * 8];
                acc[fm][fn] = __builtin_amdgcn_mfma_f32_16x16x32_bf16(afr, bfr, acc[fm][fn], 0, 0, 0);
            }
        }
        float bv0 = b1[nbase + m16], bv1 = b1[nbase + 16 + m16];
#pragma unroll
        for (int fm = 0; fm < 4; fm++)
#pragma unroll
            for (int r = 0; r < 4; r++) {
                int row = mbase + fm * 16 + quad * 4 + r;
                H1s[row * 72 + nbase + m16]      = f2b(fmaxf(acc[fm][0][r] + bv0, 0.f));
                H1s[row * 72 + nbase + 16 + m16] = f2b(fmaxf(acc[fm][1][r] + bv1, 0.f));
            }
    }
    __syncthreads();

    {
        const int mb2 = w * 32;
        floatx4 acc[2][2] = {};
#pragma unroll
        for (int kk = 0; kk < 64; kk += 32)
#pragma unroll
            for (int fn = 0; fn < 2; fn++) {
                short8v bfr = *(short8v*)&B2s[(fn * 16 + m16) * 72 + kk + quad * 8];
#pragma unroll
                for (int fm = 0; fm < 2; fm++) {
                    short8v afr = *(short8v*)&H1s[(mb2 + fm * 16 + m16) * 72 + kk + quad * 8];
                    acc[fm][fn] = __builtin_amdgcn_mfma_f32_16x16x32_bf16(afr, bfr, acc[fm][fn], 0, 0, 0);
                }
            }
        unsigned short* Cs = As;
#pragma unroll
        for (int fm = 0; fm < 2; fm++)
#pragma unroll
            for (int r = 0; r < 4; r++) {
                int row = mb2 + fm * 16 + quad * 4 + r;
                Cs[row * 40 + m16]      = f2b(acc[fm][0][r]);
                Cs[row * 40 + 16 + m16] = f2b(acc[fm][1][r]);
            }
    }
    __syncthreads();
    for (int u = tid; u < 512; u += 256) {
        int r = u >> 2, cc = u & 3;
        *(short8v*)&hw2[((size_t)l * BATCH + b0 + r) * 32 + cc * 8] =
            *(short8v*)&As[r * 40 + cc * 8];
    }
}

// ---------------------------------------------------------------------------
// LDS-free slab GEMM: MFMA operand fragments loaded straight from global
// (A rows [row][CIN], B rows [n][KTOT]; k contiguous -> 16B/lane dwordx4).
// No barriers in the K-loop; LDS used only for the coalesced bf16 epilogue.
// BM = WM*32 (2 m-waves), BN = FN*32 (2 n-waves).
// MODE 0: bf16 out + bias + relu. MODE 4: fp32 out [210-stride], masked.
// ---------------------------------------------------------------------------
template<int WM, int FN, int NTAP, int CIN, int NOUT, int STRIDE, int PAD, int LIN, int MODE>
__launch_bounds__(256)
__global__ void gemm_slab(const unsigned short* __restrict__ in,
                          const unsigned short* __restrict__ wn,
                          const float* __restrict__ bias,
                          unsigned short* __restrict__ outb,
                          float* __restrict__ outf) {
    constexpr int BM  = WM * 32;
    constexpr int BN  = FN * 32;
    constexpr int KTOT = NTAP * CIN;
    constexpr int CPOOL = (MODE == 4) ? 16 : BM * (BN + 8);
    __shared__ __align__(16) unsigned short Cs[CPOOL];
    const int tid = threadIdx.x;
    const size_t b0 = blockIdx.x * BM;
    const int n0 = blockIdx.y * BN;
    const int l  = blockIdx.z;
    const int w = tid >> 6, lane = tid & 63, quad = lane >> 4, m16 = lane & 15;
    const int wm = w >> 1, wq = w & 1;
    const int mbase = wm * (WM * 16), nbase = wq * (FN * 16);
    floatx4 acc[WM][FN] = {};

#pragma unroll
    for (int t = 0; t < NTAP; ++t) {
        int pos = STRIDE * l + t - PAD;
        if (pos < 0 || pos >= LIN) continue;
        const unsigned short* arow = in + ((size_t)pos * BATCH + b0) * CIN;
        const unsigned short* brow = wn + (size_t)n0 * KTOT + t * CIN;
#pragma unroll
        for (int k0 = 0; k0 < CIN; k0 += 32) {
            short8v bfr[FN];
#pragma unroll
            for (int fn = 0; fn < FN; fn++)
                bfr[fn] = *(const short8v*)&brow[(size_t)(nbase + fn * 16 + m16) * KTOT + k0 + quad * 8];
#pragma unroll
            for (int fm = 0; fm < WM; fm++) {
                short8v afr = *(const short8v*)&arow[(size_t)(mbase + fm * 16 + m16) * CIN + k0 + quad * 8];
#pragma unroll
                for (int fn = 0; fn < FN; fn++)
                    acc[fm][fn] = __builtin_amdgcn_mfma_f32_16x16x32_bf16(afr, bfr[fn], acc[fm][fn], 0, 0, 0);
            }
        }
    }

    if constexpr (MODE == 4) {
#pragma unroll
        for (int fn = 0; fn < FN; fn++) {
            int cg = n0 + nbase + fn * 16 + m16;
            float bv = (cg < 210) ? bias[cg] : 0.f;
            if (cg < 210) {
#pragma unroll
                for (int fm = 0; fm < WM; fm++)
#pragma unroll
                    for (int r = 0; r < 4; r++) {
                        size_t row = b0 + mbase + fm * 16 + quad * 4 + r;
                        outf[row * 210 + cg] = acc[fm][fn][r] + bv;
                    }
            }
        }
    } else {
        float bv[FN];
#pragma unroll
        for (int fn = 0; fn < FN; fn++) bv[fn] = bias[n0 + nbase + fn * 16 + m16];
#pragma unroll
        for (int fm = 0; fm < WM; fm++)
#pragma unroll
            for (int r = 0; r < 4; r++) {
                int row = mbase + fm * 16 + quad * 4 + r;
#pragma unroll
                for (int fn = 0; fn < FN; fn++)
                    Cs[row * (BN + 8) + nbase + fn * 16 + m16] =
                        f2b(fmaxf(acc[fm][fn][r] + bv[fn], 0.f));
            }
        __syncthreads();
        for (int u = tid; u < BM * (BN / 8); u += 256) {
            int r = u / (BN / 8), cc = u % (BN / 8);
            *(short8v*)&outb[((size_t)l * BATCH + b0 + r) * NOUT + n0 + cc * 8] =
                *(short8v*)&Cs[r * (BN + 8) + cc * 8];
        }
    }
}

// ---------------------------------------------------------------------------
// fc1 split-K, LDS-free direct-fragment version. grid (64, 1, 6); z handles
// taps {2z, 2z+1} (K=512). Waves 2x2, each 64x64. fp32 partials out.
// ---------------------------------------------------------------------------
__launch_bounds__(256)
__global__ void fc1_splitk(const unsigned short* __restrict__ c3,
                           const unsigned short* __restrict__ wf1,
                           float* __restrict__ part) {
    const int tid = threadIdx.x;
    const size_t b0 = blockIdx.x * 128;
    const int kg = blockIdx.z;
    const int w = tid >> 6, lane = tid & 63, quad = lane >> 4, m16 = lane & 15;
    const int wm = w >> 1, wq = w & 1;
    const int mbase = wm * 64, nbase = wq * 64;
    floatx4 acc[4][4] = {};

#pragma unroll
    for (int tt = 0; tt < 2; tt++) {
        const int t = kg * 2 + tt;
        const unsigned short* arow = c3 + ((size_t)t * BATCH + b0) * 256;
        const unsigned short* brow = wf1 + t * 256;
#pragma unroll
        for (int k0 = 0; k0 < 256; k0 += 32) {
            short8v bfr[4];
#pragma unroll
            for (int fn = 0; fn < 4; fn++)
                bfr[fn] = *(const short8v*)&brow[(size_t)(nbase + fn * 16 + m16) * 3072 + k0 + quad * 8];
#pragma unroll
            for (int fm = 0; fm < 4; fm++) {
                short8v afr = *(const short8v*)&arow[(size_t)(mbase + fm * 16 + m16) * 256 + k0 + quad * 8];
#pragma unroll
                for (int fn = 0; fn < 4; fn++)
                    acc[fm][fn] = __builtin_amdgcn_mfma_f32_16x16x32_bf16(afr, bfr[fn], acc[fm][fn], 0, 0, 0);
            }
        }
    }
    float* pg = part + (size_t)kg * BATCH * 128;
#pragma unroll
    for (int fm = 0; fm < 4; fm++)
#pragma unroll
        for (int r = 0; r < 4; r++) {
            size_t row = b0 + mbase + fm * 16 + quad * 4 + r;
#pragma unroll
            for (int fn = 0; fn < 4; fn++)
                pg[row * 128 + nbase + fn * 16 + m16] = acc[fm][fn][r];
        }
}

// ---------------------------------------------------------------------------
__launch_bounds__(256)
__global__ void fc1_reduce(const float* __restrict__ part, const float* __restrict__ bias,
                           float* __restrict__ feat, unsigned short* __restrict__ fr) {
    const size_t idx = (size_t)blockIdx.x * 256 + threadIdx.x;
    const size_t row = idx >> 5;
    const int    c4  = (int)(idx & 31);
    float4 s = *(const float4*)&bias[c4 * 4];
#pragma unroll
    for (int z = 0; z < 6; z++) {
        float4 p = *(const float4*)&part[(z * BATCH + row) * 128 + c4 * 4];
        s.x += p.x; s.y += p.y; s.z += p.z; s.w += p.w;
    }
    *(float4*)&feat[row * 128 + c4 * 4] = s;
    unsigned int d0 = (unsigned int)f2b(fmaxf(s.x, 0.f)) |
                      ((unsigned int)f2b(fmaxf(s.y, 0.f)) << 16);
    unsigned int d1 = (unsigned int)f2b(fmaxf(s.z, 0.f)) |
                      ((unsigned int)f2b(fmaxf(s.w, 0.f)) << 16);
    *(uint2*)&fr[row * 128 + c4 * 4] = make_uint2(d0, d1);
}

// ---------------------------------------------------------------------------
extern "C" void kernel_launch(void* const* d_in, const int* in_sizes, int n_in,
                              void* d_out, int out_size, void* d_ws, size_t ws_size,
                              hipStream_t stream) {
    const float* src  = (const float*)d_in[0];
    const int*   eidx = (const int*)  d_in[1];
    const float* g1w  = (const float*)d_in[2];
    const float* g1b  = (const float*)d_in[3];
    const float* g2w  = (const float*)d_in[4];
    const float* g2b  = (const float*)d_in[5];
    const float* cv1w = (const float*)d_in[6];
    const float* cv1b = (const float*)d_in[7];
    const float* cv2w = (const float*)d_in[8];
    const float* cv2b = (const float*)d_in[9];
    const float* cv3w = (const float*)d_in[10];
    const float* cv3b = (const float*)d_in[11];
    const float* fc1w = (const float*)d_in[12];
    const float* fc1b = (const float*)d_in[13];
    const float* cl1w = (const float*)d_in[14];
    const float* cl1b = (const float*)d_in[15];
    const float* cl2w = (const float*)d_in[16];
    const float* cl2b = (const float*)d_in[17];

    unsigned short* ws16 = (unsigned short*)d_ws;
    float* wsF = (float*)d_ws;
    float* out = (float*)d_out;

    unsigned short* xt  = ws16 + R1_OFF;
    unsigned short* xa  = ws16 + R0_OFF;
    unsigned short* hw2 = ws16 + R1_OFF;
    unsigned short* h2  = ws16 + R0_OFF;
    unsigned short* c1  = ws16 + R1_OFF;
    unsigned short* c2  = ws16 + R0_OFF;
    unsigned short* c3  = ws16 + R1_OFF;
    float*          part = wsF;              // aliases dead c2 (R0)
    unsigned short* fr  = ws16 + FR_OFF;
    unsigned short* r2  = ws16 + R2_OFF;
    unsigned short* w1n = ws16 + W1N_OFF;
    unsigned short* w2n = ws16 + W2N_OFF;
    unsigned short* wc1 = ws16 + WC1_OFF;
    unsigned short* wc2 = ws16 + WC2_OFF;
    unsigned short* wc3 = ws16 + WC3_OFF;
    unsigned short* wf1 = ws16 + WF1_OFF;
    unsigned short* wl1 = ws16 + WL1_OFF;
    unsigned short* wl2 = ws16 + WL2_OFF;
    unsigned short* ah  = ws16 + AH_OFF;

    float* feat_out = out + 8192ull * 210ull;

    prep_edges<<<1, 256, 0, stream>>>(eidx, ah);
    prep_weights<<<2345, 256, 0, stream>>>(g1w, g2w, cv1w, cv2w, cv3w, fc1w, cl1w, cl2w,
                                           ws16 + WT_OFF);
    trans16<<<1024, 256, 0, stream>>>(src, xt);
    agg_mm<16, false><<<512, 256, 0, stream>>>(xt, ah, nullptr, xa);
    gcn12<<<dim3(64, 1, 96), 256, 0, stream>>>(xa, w1n, w2n, g1b, hw2);
    agg_mm<32, true><<<1024, 256, 0, stream>>>(hw2, ah, g2b, h2);
    // conv1: BM=256, BN=64
    gemm_slab<8, 2, 7, 32, 64, 2, 3, 96, 0>
        <<<dim3(32, 1, 48), 256, 0, stream>>>(h2, wc1, cv1b, c1, nullptr);
    // conv2: BM=128, BN=128
    gemm_slab<4, 4, 5, 64, 128, 2, 2, 48, 0>
        <<<dim3(64, 1, 24), 256, 0, stream>>>(c1, wc2, cv2b, c2, nullptr);
    // conv3: BM=128, BN=128 (y=2)
    gemm_slab<4, 4, 3, 128, 256, 2, 1, 24, 0>
        <<<dim3(64, 2, 12), 256, 0, stream>>>(c2, wc3, cv3b, c3, nullptr);
    fc1_splitk<<<dim3(64, 1, 6), 256, 0, stream>>>(c3, wf1, part);
    fc1_reduce<<<1024, 256, 0, stream>>>(part, fc1b, feat_out, fr);
    gemm_slab<2, 2, 1, 128, 128, 1, 0, 1, 0>
        <<<dim3(128, 2, 1), 256, 0, stream>>>(fr, wl1, cl1b, r2, nullptr);
    gemm_slab<2, 2, 1, 128, 256, 1, 0, 1, 4>
        <<<dim3(128, 4, 1), 256, 0, stream>>>(r2, wl2, cl2b, nullptr, out);
}

// Round 9
// 344.887 us; speedup vs baseline: 1.2342x; 1.2342x over previous
//
#include <hip/hip_runtime.h>

// ---------------------------------------------------------------------------
// TimeSeriesGCN — bf16 MFMA pipeline, batch-as-M GEMMs on position-major slabs.
// prep_edges:  edge_index -> dense bf16 Ahat[96][96]
// trans16:     src -> xt[96][8192][16] (bf16 transpose only)
// agg_mm<16>:  xt -> xa = Ahat @ xt            (dense-GEMM aggregation)
// gcn12:       xa(16ch) -> hw2[96][8192][32]
// agg_mm<32>:  hw2 -> h2 = relu(Ahat @ hw2 + b2)
// conv1/2/3:   hybrid GEMMs: A staged in LDS, B direct-from-global in a
//              fragment-swizzled layout (1 KB contiguous per wave-load)
// fc1_splitk:  c3 -> fp32 partials (6-way split-K, same hybrid)
// fc1_reduce:  partials -> feat (fp32 d_out) + fr (bf16 relu)
// cls1/cls2:   same template
// ---------------------------------------------------------------------------

typedef __attribute__((ext_vector_type(8))) short short8v;
typedef __attribute__((ext_vector_type(4))) float floatx4;

#define N_NODE 96
#define E_TOT  864
#define BATCH  8192ull

// ws layout, ushort elements
#define R0_OFF   0ull
#define R1_OFF   25165824ull
#define FR_OFF   50331648ull
#define R2_OFF   51380224ull
#define WT_OFF   52428800ull
#define W1N_OFF  (WT_OFF + 0)
#define W2N_OFF  (WT_OFF + 2048)
#define WC1_OFF  (WT_OFF + 4096)      // fragswizzled [4g][7ks][64][8]
#define WC2_OFF  (WT_OFF + 18432)     // [8g][10ks][64][8]
#define WC3_OFF  (WT_OFF + 59392)     // [16g][12ks][64][8]
#define WF1_OFF  (WT_OFF + 157696)    // [8g][96ks][64][8]
#define WL1_OFF  (WT_OFF + 550912)    // [8g][4ks][64][8]
#define WL2_OFF  (WT_OFF + 567296)    // [16g][4ks][64][8]
#define AH_OFF   (WT_OFF + 600064)    // dense Ahat bf16 [96][96]

__device__ __forceinline__ unsigned short f2b(float f) {
    unsigned int u = __builtin_bit_cast(unsigned int, f);
    u += 0x7fffu + ((u >> 16) & 1u);
    return (unsigned short)(u >> 16);
}
__device__ __forceinline__ float b2f(unsigned short h) {
    unsigned int u = ((unsigned int)h) << 16;
    return __builtin_bit_cast(float, u);
}

// ---------------------------------------------------------------------------
__global__ void prep_edges(const int* __restrict__ eidx, unsigned short* __restrict__ adense) {
    __shared__ int rowv[E_TOT];
    __shared__ int colv[E_TOT];
    __shared__ int degi[N_NODE];
    __shared__ float dinv[N_NODE];
    __shared__ float ad[96 * 96];
    const int tid = threadIdx.x;
    for (int e = tid; e < E_TOT; e += 256) {
        int r, c;
        if (e < 768) { r = eidx[e]; c = eidx[768 + e]; }
        else         { r = e - 768; c = r; }
        rowv[e] = r; colv[e] = c;
    }
    for (int n = tid; n < N_NODE; n += 256) degi[n] = 0;
    for (int i = tid; i < 9216; i += 256) ad[i] = 0.f;
    __syncthreads();
    for (int e = tid; e < E_TOT; e += 256) atomicAdd(&degi[rowv[e]], 1);
    __syncthreads();
    for (int n = tid; n < N_NODE; n += 256)
        dinv[n] = rsqrtf(fmaxf((float)degi[n], 1e-12f));
    __syncthreads();
    for (int e = tid; e < E_TOT; e += 256)
        atomicAdd(&ad[rowv[e] * 96 + colv[e]], dinv[rowv[e]] * dinv[colv[e]]);
    __syncthreads();
    for (int i = tid; i < 9216; i += 256) adense[i] = f2b(ad[i]);
}

// ---------------------------------------------------------------------------
// Fragment-swizzled B layout: for group g (16 n-cols), kstep ks (32 k),
// lane = quad*16 + n16, j in [0,8): element = B[g*16+n16][ks*32+quad*8+j].
// A wave's B-fragment load is 64 lanes x 16 B fully contiguous (1 KB).
// ---------------------------------------------------------------------------
__global__ void prep_weights(const float* __restrict__ g1w, const float* __restrict__ g2w,
                             const float* __restrict__ w1, const float* __restrict__ w2,
                             const float* __restrict__ w3, const float* __restrict__ f1,
                             const float* __restrict__ l1, const float* __restrict__ l2,
                             unsigned short* __restrict__ wt) {
    long idx = (long)blockIdx.x * 256 + threadIdx.x;
    if (idx >= 600064) return;
    float v;
    if (idx < 2048) {                      // w1n[o][c] (gcn12, unswizzled)
        int o = idx >> 5, c = idx & 31;
        v = (c < 16) ? g1w[c * 64 + o] : 0.f;
    } else if (idx < 4096) {               // w2n[g][c] (gcn12, unswizzled)
        long j = idx - 2048; int g = j >> 6, c = j & 63;
        v = g2w[c * 32 + g];
    } else {
        long base, KS;
        int region;
        if      (idx < 18432)  { base = 4096;   KS = 7;  region = 0; }
        else if (idx < 59392)  { base = 18432;  KS = 10; region = 1; }
        else if (idx < 157696) { base = 59392;  KS = 12; region = 2; }
        else if (idx < 550912) { base = 157696; KS = 96; region = 3; }
        else if (idx < 567296) { base = 550912; KS = 4;  region = 4; }
        else                   { base = 567296; KS = 4;  region = 5; }
        long local = idx - base;
        long g  = local / (KS * 512);
        long rm = local % (KS * 512);
        long ks = rm / 512;
        int lane = (int)((rm % 512) / 8);
        int j    = (int)(rm % 8);
        int quad = lane >> 4, n16 = lane & 15;
        int n = (int)(g * 16 + n16);
        int k = (int)(ks * 32 + quad * 8 + j);
        switch (region) {
            case 0: { int t = k / 32,  c = k % 32;  v = w1[n * 224 + c * 7 + t]; } break;
            case 1: { int t = k / 64,  c = k % 64;  v = w2[n * 320 + c * 5 + t]; } break;
            case 2: { int t = k / 128, c = k % 128; v = w3[n * 384 + c * 3 + t]; } break;
            case 3: { int t = k / 256, o = k % 256; v = f1[(o * 12 + t) * 128 + n]; } break;
            case 4: v = l1[k * 128 + n]; break;
            default: v = (n < 210) ? l2[k * 210 + n] : 0.f; break;
        }
    }
    wt[idx] = f2b(v);
}

// ---------------------------------------------------------------------------
__launch_bounds__(256)
__global__ void trans16(const float* __restrict__ src, unsigned short* __restrict__ xt) {
    __shared__ __align__(16) float xs[8 * 1544];
    const int tid = threadIdx.x;
    const int b0 = blockIdx.x * 8;
    for (int u = tid; u < 3072; u += 256) {
        int bl = u / 384, j = u % 384;
        *(float4*)&xs[bl * 1544 + j * 4] =
            *(const float4*)&src[((size_t)(b0 + bl)) * 1536 + j * 4];
    }
    __syncthreads();
    for (int u = tid; u < 768; u += 256) {
        int n = u >> 3, bl = u & 7;
        const float* base = &xs[bl * 1544 + n];
        unsigned int d[8];
#pragma unroll
        for (int c2 = 0; c2 < 8; c2++)
            d[c2] = (unsigned int)f2b(base[(2 * c2) * 96]) |
                    ((unsigned int)f2b(base[(2 * c2 + 1) * 96]) << 16);
        unsigned int* o = (unsigned int*)(xt + ((size_t)n * BATCH + b0 + bl) * 16);
        *(uint4*)&o[0] = make_uint4(d[0], d[1], d[2], d[3]);
        *(uint4*)&o[4] = make_uint4(d[4], d[5], d[6], d[7]);
    }
}

// ---------------------------------------------------------------------------
template<int CH, bool RELU>
__launch_bounds__(256)
__global__ void agg_mm(const unsigned short* __restrict__ in,
                       const unsigned short* __restrict__ adense,
                       const float* __restrict__ bias,
                       unsigned short* __restrict__ outp) {
    const size_t NCOL = 8192ull * CH;
    __shared__ __align__(16) unsigned short Al[96 * 104];
    __shared__ __align__(16) unsigned short Bs[96 * 264];
    const int tid = threadIdx.x;
    const size_t c0 = (size_t)blockIdx.x * 256;
    const int w = tid >> 6, lane = tid & 63, quad = lane >> 4, m16 = lane & 15;

    for (int u = tid; u < 1152; u += 256) {
        int r = u / 12, q = u % 12;
        *(short8v*)&Al[r * 104 + q * 8] = *(const short8v*)&adense[r * 96 + q * 8];
    }
    for (int u = tid; u < 3072; u += 256) {
        int r = u >> 5, q = u & 31;
        *(uint4*)&Bs[r * 264 + q * 8] = *(const uint4*)&in[(size_t)r * NCOL + c0 + q * 8];
    }
    __syncthreads();

    floatx4 acc[6][4] = {};
    const int nb = w * 64;
#pragma unroll
    for (int kk = 0; kk < 96; kk += 32) {
        short8v bfr[4];
#pragma unroll
        for (int fn = 0; fn < 4; fn++) {
            const int col = nb + fn * 16 + m16;
#pragma unroll
            for (int j = 0; j < 8; j++)
                bfr[fn][j] = (short)Bs[(kk + quad * 8 + j) * 264 + col];
        }
#pragma unroll
        for (int fm = 0; fm < 6; fm++) {
            short8v afr = *(short8v*)&Al[(fm * 16 + m16) * 104 + kk + quad * 8];
#pragma unroll
            for (int fn = 0; fn < 4; fn++)
                acc[fm][fn] = __builtin_amdgcn_mfma_f32_16x16x32_bf16(afr, bfr[fn], acc[fm][fn], 0, 0, 0);
        }
    }

#pragma unroll
    for (int fm = 0; fm < 6; fm++) {
#pragma unroll
        for (int fn = 0; fn < 4; fn++) {
            const int col = nb + fn * 16 + m16;
            float bv = 0.f;
            if constexpr (RELU) bv = bias[col & (CH - 1)];
#pragma unroll
            for (int r = 0; r < 4; r++) {
                int node = fm * 16 + quad * 4 + r;
                float v = acc[fm][fn][r];
                if constexpr (RELU) v = fmaxf(v + bv, 0.f);
                outp[(size_t)node * NCOL + c0 + col] = f2b(v);
            }
        }
    }
}

// ---------------------------------------------------------------------------
__launch_bounds__(256)
__global__ void gcn12(const unsigned short* __restrict__ xa,
                      const unsigned short* __restrict__ w1n,
                      const unsigned short* __restrict__ w2n,
                      const float* __restrict__ b1, unsigned short* __restrict__ hw2) {
    __shared__ __align__(16) unsigned short As[128 * 40];
    __shared__ __align__(16) unsigned short B1s[64 * 40];
    __shared__ __align__(16) unsigned short H1s[128 * 72];
    __shared__ __align__(16) unsigned short B2s[32 * 72];
    const int tid = threadIdx.x;
    const size_t b0 = blockIdx.x * 128;
    const int l = blockIdx.z;
    const int w = tid >> 6, lane = tid & 63, quad = lane >> 4, m16 = lane & 15;

    short8v zz = {0, 0, 0, 0, 0, 0, 0, 0};
    for (int u = tid; u < 512; u += 256) {
        int r = u >> 2, cc = u & 3;
        *(short8v*)&As[r * 40 + cc * 8] = (cc < 2)
            ? *(const short8v*)&xa[((size_t)l * BATCH + b0 + r) * 16 + cc * 8]
            : zz;
    }
    for (int u = tid; u < 256; u += 256) {
        int r = u >> 2, cc = u & 3;
        *(short8v*)&B1s[r * 40 + cc * 8] = *(const short8v*)&w1n[r * 32 + cc * 8];
    }
    for (int u = tid; u < 256; u += 256) {
        int r = u >> 3, cc = u & 7;
        *(short8v*)&B2s[r * 72 + cc * 8] = *(const short8v*)&w2n[r * 64 + cc * 8];
    }
    __syncthreads();

    {
        const int wm = w >> 1, wq = w & 1;
        const int mbase = wm * 64, nbase = wq * 32;
        floatx4 acc[4][2] = {};
#pragma unroll
        for (int fn = 0; fn < 2; fn++) {
            short8v bfr = *(short8v*)&B1s[(nbase + fn * 16 + m16) * 40 + quad * 8];
#pragma unroll
            for (int fm = 0; fm < 4; fm++) {
                short8v afr = *(short8v*)&As[(mbase + fm * 16 + m16) * 40 + quad * 8];
                acc[fm][fn] = __builtin_amdgcn_mfma_f32_16x16x32_bf16(afr, bfr, acc[fm][fn], 0, 0, 0);
            }
        }
        float bv0 = b1[nbase + m16], bv1 = b1[nbase + 16 + m16];
#pragma unroll
        for (int fm = 0; fm < 4; fm++)
#pragma unroll
            for (int r = 0; r < 4; r++) {
                int row = mbase + fm * 16 + quad * 4 + r;
                H1s[row * 72 + nbase + m16]      = f2b(fmaxf(acc[fm][0][r] + bv0, 0.f));
                H1s[row * 72 + nbase + 16 + m16] = f2b(fmaxf(acc[fm][1][r] + bv1, 0.f));
            }
    }
    __syncthreads();

    {
        const int mb2 = w * 32;
        floatx4 acc[2][2] = {};
#pragma unroll
        for (int kk = 0; kk < 64; kk += 32)
#pragma unroll
            for (int fn = 0; fn < 2; fn++) {
                short8v bfr = *(short8v*)&B2s[(fn * 16 + m16) * 72 + kk + quad * 8];
#pragma unroll
                for (int fm = 0; fm < 2; fm++) {
                    short8v afr = *(short8v*)&H1s[(mb2 + fm * 16 + m16) * 72 + kk + quad * 8];
                    acc[fm][fn] = __builtin_amdgcn_mfma_f32_16x16x32_bf16(afr, bfr, acc[fm][fn], 0, 0, 0);
                }
            }
        unsigned short* Cs = As;
#pragma unroll
        for (int fm = 0; fm < 2; fm++)
#pragma unroll
            for (int r = 0; r < 4; r++) {
                int row = mb2 + fm * 16 + quad * 4 + r;
                Cs[row * 40 + m16]      = f2b(acc[fm][0][r]);
                Cs[row * 40 + 16 + m16] = f2b(acc[fm][1][r]);
            }
    }
    __syncthreads();
    for (int u = tid; u < 512; u += 256) {
        int r = u >> 2, cc = u & 3;
        *(short8v*)&hw2[((size_t)l * BATCH + b0 + r) * 32 + cc * 8] =
            *(short8v*)&As[r * 40 + cc * 8];
    }
}

// ---------------------------------------------------------------------------
// Hybrid slab GEMM: A staged in LDS (latency-batched, coalesced); B fragments
// loaded directly from global in fragswizzled layout (contiguous 1 KB/wave,
// L1/L2-resident, no LDS round-trip). BM = WM*32, BN = FN*32, waves 2x2.
// MODE 0: bf16 out + bias + relu. MODE 4: fp32 out [210-stride], masked.
// ---------------------------------------------------------------------------
template<int WM, int FN, int NTAP, int CIN, int NOUT, int STRIDE, int PAD, int LIN, int BK, int MODE>
__launch_bounds__(256)
__global__ void gemm_slab(const unsigned short* __restrict__ in,
                          const unsigned short* __restrict__ wn,
                          const float* __restrict__ bias,
                          unsigned short* __restrict__ outb,
                          float* __restrict__ outf) {
    constexpr int BM  = WM * 32;
    constexpr int BN  = FN * 32;
    constexpr int BKP = BK + 8;
    constexpr int CPT = CIN / BK;
    constexpr int NC  = NTAP * CPT;
    constexpr int KS  = NTAP * CIN / 32;     // fragswizzle ksteps
    constexpr int SZ1 = BM * BKP;
    constexpr int SZ2 = (MODE == 4) ? 16 : BM * (BN + 8);
    constexpr int POOL = SZ1 > SZ2 ? SZ1 : SZ2;
    __shared__ __align__(16) unsigned short pool[POOL];
    unsigned short* As = pool;
    const int tid = threadIdx.x;
    const size_t b0 = blockIdx.x * BM;
    const int n0 = blockIdx.y * BN;
    const int l  = blockIdx.z;
    const int w = tid >> 6, lane = tid & 63, quad = lane >> 4, m16 = lane & 15;
    const int wm = w >> 1, wq = w & 1;
    const int mbase = wm * (WM * 16), nbase = wq * (FN * 16);
    const int gw = (n0 + nbase) >> 4;        // first 16-col weight group
    floatx4 acc[WM][FN] = {};

    for (int ch = 0; ch < NC; ++ch) {
        int t = ch / CPT, inner = ch % CPT;
        int pos = STRIDE * l + t - PAD;
        if (pos < 0 || pos >= LIN) continue;
        const unsigned short* ag = in + ((size_t)pos * BATCH + b0) * CIN + inner * BK;
        for (int u = tid; u < BM * (BK / 8); u += 256) {
            int r = u / (BK / 8), cc = u % (BK / 8);
            *(short8v*)&As[r * BKP + cc * 8] = *(const short8v*)&ag[(size_t)r * CIN + cc * 8];
        }
        __syncthreads();
        const int kbase = t * CIN + inner * BK;
#pragma unroll
        for (int kk = 0; kk < BK; kk += 32) {
            const int ksG = (kbase + kk) >> 5;
            short8v bfr[FN];
#pragma unroll
            for (int fn = 0; fn < FN; fn++)
                bfr[fn] = *(const short8v*)&wn[(((size_t)(gw + fn) * KS + ksG) << 9) + lane * 8];
#pragma unroll
            for (int fm = 0; fm < WM; fm++) {
                short8v afr = *(short8v*)&As[(mbase + fm * 16 + m16) * BKP + kk + quad * 8];
#pragma unroll
                for (int fn = 0; fn < FN; fn++)
                    acc[fm][fn] = __builtin_amdgcn_mfma_f32_16x16x32_bf16(afr, bfr[fn], acc[fm][fn], 0, 0, 0);
            }
        }
        __syncthreads();
    }

    if constexpr (MODE == 4) {
#pragma unroll
        for (int fn = 0; fn < FN; fn++) {
            int cg = n0 + nbase + fn * 16 + m16;
            float bv = (cg < 210) ? bias[cg] : 0.f;
            if (cg < 210) {
#pragma unroll
                for (int fm = 0; fm < WM; fm++)
#pragma unroll
                    for (int r = 0; r < 4; r++) {
                        size_t row = b0 + mbase + fm * 16 + quad * 4 + r;
                        outf[row * 210 + cg] = acc[fm][fn][r] + bv;
                    }
            }
        }
    } else {
        float bv[FN];
#pragma unroll
        for (int fn = 0; fn < FN; fn++) bv[fn] = bias[n0 + nbase + fn * 16 + m16];
        unsigned short* Cs = pool;
#pragma unroll
        for (int fm = 0; fm < WM; fm++)
#pragma unroll
            for (int r = 0; r < 4; r++) {
                int row = mbase + fm * 16 + quad * 4 + r;
#pragma unroll
                for (int fn = 0; fn < FN; fn++)
                    Cs[row * (BN + 8) + nbase + fn * 16 + m16] =
                        f2b(fmaxf(acc[fm][fn][r] + bv[fn], 0.f));
            }
        __syncthreads();
        for (int u = tid; u < BM * (BN / 8); u += 256) {
            int r = u / (BN / 8), cc = u % (BN / 8);
            *(short8v*)&outb[((size_t)l * BATCH + b0 + r) * NOUT + n0 + cc * 8] =
                *(short8v*)&Cs[r * (BN + 8) + cc * 8];
        }
    }
}

// ---------------------------------------------------------------------------
// fc1 split-K, hybrid: A (c3) staged in LDS; B (wf1) direct fragswizzled.
// grid (64, 1, 6); z handles taps {2z, 2z+1} (K=512). Waves 2x2, each 64x64.
// ---------------------------------------------------------------------------
__launch_bounds__(256)
__global__ void fc1_splitk(const unsigned short* __restrict__ c3,
                           const unsigned short* __restrict__ wf1,
                           float* __restrict__ part) {
    __shared__ __align__(16) unsigned short As[128 * 72];
    const int tid = threadIdx.x;
    const size_t b0 = blockIdx.x * 128;
    const int kg = blockIdx.z;
    const int w = tid >> 6, lane = tid & 63, quad = lane >> 4, m16 = lane & 15;
    const int wm = w >> 1, wq = w & 1;
    const int mbase = wm * 64, nbase = wq * 64;
    const int gw = nbase >> 4;
    floatx4 acc[4][4] = {};

#pragma unroll
    for (int tt = 0; tt < 2; tt++) {
        const int t = kg * 2 + tt;
#pragma unroll
        for (int inner = 0; inner < 4; inner++) {
            const unsigned short* ag = c3 + ((size_t)t * BATCH + b0) * 256 + inner * 64;
            for (int u = tid; u < 1024; u += 256) {
                int r = u >> 3, cc = u & 7;
                *(short8v*)&As[r * 72 + cc * 8] = *(const short8v*)&ag[(size_t)r * 256 + cc * 8];
            }
            __syncthreads();
            const int kbase = t * 256 + inner * 64;
#pragma unroll
            for (int kk = 0; kk < 64; kk += 32) {
                const int ksG = (kbase + kk) >> 5;    // KS = 96
                short8v bfr[4];
#pragma unroll
                for (int fn = 0; fn < 4; fn++)
                    bfr[fn] = *(const short8v*)&wf1[(((size_t)(gw + fn) * 96 + ksG) << 9) + lane * 8];
#pragma unroll
                for (int fm = 0; fm < 4; fm++) {
                    short8v afr = *(short8v*)&As[(mbase + fm * 16 + m16) * 72 + kk + quad * 8];
#pragma unroll
                    for (int fn = 0; fn < 4; fn++)
                        acc[fm][fn] = __builtin_amdgcn_mfma_f32_16x16x32_bf16(afr, bfr[fn], acc[fm][fn], 0, 0, 0);
                }
            }
            __syncthreads();
        }
    }
    float* pg = part + (size_t)kg * BATCH * 128;
#pragma unroll
    for (int fm = 0; fm < 4; fm++)
#pragma unroll
        for (int r = 0; r < 4; r++) {
            size_t row = b0 + mbase + fm * 16 + quad * 4 + r;
#pragma unroll
            for (int fn = 0; fn < 4; fn++)
                pg[row * 128 + nbase + fn * 16 + m16] = acc[fm][fn][r];
        }
}

// ---------------------------------------------------------------------------
__launch_bounds__(256)
__global__ void fc1_reduce(const float* __restrict__ part, const float* __restrict__ bias,
                           float* __restrict__ feat, unsigned short* __restrict__ fr) {
    const size_t idx = (size_t)blockIdx.x * 256 + threadIdx.x;
    const size_t row = idx >> 5;
    const int    c4  = (int)(idx & 31);
    float4 s = *(const float4*)&bias[c4 * 4];
#pragma unroll
    for (int z = 0; z < 6; z++) {
        float4 p = *(const float4*)&part[(z * BATCH + row) * 128 + c4 * 4];
        s.x += p.x; s.y += p.y; s.z += p.z; s.w += p.w;
    }
    *(float4*)&feat[row * 128 + c4 * 4] = s;
    unsigned int d0 = (unsigned int)f2b(fmaxf(s.x, 0.f)) |
                      ((unsigned int)f2b(fmaxf(s.y, 0.f)) << 16);
    unsigned int d1 = (unsigned int)f2b(fmaxf(s.z, 0.f)) |
                      ((unsigned int)f2b(fmaxf(s.w, 0.f)) << 16);
    *(uint2*)&fr[row * 128 + c4 * 4] = make_uint2(d0, d1);
}

// ---------------------------------------------------------------------------
extern "C" void kernel_launch(void* const* d_in, const int* in_sizes, int n_in,
                              void* d_out, int out_size, void* d_ws, size_t ws_size,
                              hipStream_t stream) {
    const float* src  = (const float*)d_in[0];
    const int*   eidx = (const int*)  d_in[1];
    const float* g1w  = (const float*)d_in[2];
    const float* g1b  = (const float*)d_in[3];
    const float* g2w  = (const float*)d_in[4];
    const float* g2b  = (const float*)d_in[5];
    const float* cv1w = (const float*)d_in[6];
    const float* cv1b = (const float*)d_in[7];
    const float* cv2w = (const float*)d_in[8];
    const float* cv2b = (const float*)d_in[9];
    const float* cv3w = (const float*)d_in[10];
    const float* cv3b = (const float*)d_in[11];
    const float* fc1w = (const float*)d_in[12];
    const float* fc1b = (const float*)d_in[13];
    const float* cl1w = (const float*)d_in[14];
    const float* cl1b = (const float*)d_in[15];
    const float* cl2w = (const float*)d_in[16];
    const float* cl2b = (const float*)d_in[17];

    unsigned short* ws16 = (unsigned short*)d_ws;
    float* wsF = (float*)d_ws;
    float* out = (float*)d_out;

    unsigned short* xt  = ws16 + R1_OFF;
    unsigned short* xa  = ws16 + R0_OFF;
    unsigned short* hw2 = ws16 + R1_OFF;
    unsigned short* h2  = ws16 + R0_OFF;
    unsigned short* c1  = ws16 + R1_OFF;
    unsigned short* c2  = ws16 + R0_OFF;
    unsigned short* c3  = ws16 + R1_OFF;
    float*          part = wsF;              // aliases dead c2 (R0)
    unsigned short* fr  = ws16 + FR_OFF;
    unsigned short* r2  = ws16 + R2_OFF;
    unsigned short* w1n = ws16 + W1N_OFF;
    unsigned short* w2n = ws16 + W2N_OFF;
    unsigned short* wc1 = ws16 + WC1_OFF;
    unsigned short* wc2 = ws16 + WC2_OFF;
    unsigned short* wc3 = ws16 + WC3_OFF;
    unsigned short* wf1 = ws16 + WF1_OFF;
    unsigned short* wl1 = ws16 + WL1_OFF;
    unsigned short* wl2 = ws16 + WL2_OFF;
    unsigned short* ah  = ws16 + AH_OFF;

    float* feat_out = out + 8192ull * 210ull;

    prep_edges<<<1, 256, 0, stream>>>(eidx, ah);
    prep_weights<<<2345, 256, 0, stream>>>(g1w, g2w, cv1w, cv2w, cv3w, fc1w, cl1w, cl2w,
                                           ws16 + WT_OFF);
    trans16<<<1024, 256, 0, stream>>>(src, xt);
    agg_mm<16, false><<<512, 256, 0, stream>>>(xt, ah, nullptr, xa);
    gcn12<<<dim3(64, 1, 96), 256, 0, stream>>>(xa, w1n, w2n, g1b, hw2);
    agg_mm<32, true><<<1024, 256, 0, stream>>>(hw2, ah, g2b, h2);
    // conv1: BM=256, BN=64, BK=32
    gemm_slab<8, 2, 7, 32, 64, 2, 3, 96, 32, 0>
        <<<dim3(32, 1, 48), 256, 0, stream>>>(h2, wc1, cv1b, c1, nullptr);
    // conv2: BM=128, BN=128, BK=64
    gemm_slab<4, 4, 5, 64, 128, 2, 2, 48, 64, 0>
        <<<dim3(64, 1, 24), 256, 0, stream>>>(c1, wc2, cv2b, c2, nullptr);
    // conv3: BM=128, BN=128 (y=2), BK=128 (one stage per tap)
    gemm_slab<4, 4, 3, 128, 256, 2, 1, 24, 128, 0>
        <<<dim3(64, 2, 12), 256, 0, stream>>>(c2, wc3, cv3b, c3, nullptr);
    fc1_splitk<<<dim3(64, 1, 6), 256, 0, stream>>>(c3, wf1, part);
    fc1_reduce<<<1024, 256, 0, stream>>>(part, fc1b, feat_out, fr);
    gemm_slab<2, 2, 1, 128, 128, 1, 0, 1, 64, 0>
        <<<dim3(128, 2, 1), 256, 0, stream>>>(fr, wl1, cl1b, r2, nullptr);
    gemm_slab<2, 2, 1, 128, 256, 1, 0, 1, 64, 4>
        <<<dim3(128, 4, 1), 256, 0, stream>>>(r2, wl2, cl2b, nullptr, out);
}

// Round 10
// 335.309 us; speedup vs baseline: 1.2694x; 1.0286x over previous
//
#include <hip/hip_runtime.h>

// ---------------------------------------------------------------------------
// TimeSeriesGCN — bf16 MFMA pipeline, batch-as-M GEMMs on position-major slabs.
// prep_edges:  edge_index -> dense bf16 Ahat[96][96]
// trans16:     src -> xt[96][8192][16] (bf16 transpose only)
// agg_mm<16>:  xt -> xa = Ahat @ xt            (dense-GEMM aggregation)
// gcn12:       xa(16ch) -> hw2[96][8192][32]
// agg_mm<32>:  hw2 -> h2 = relu(Ahat @ hw2 + b2)
// conv1/2/3:   pipelined hybrid GEMMs: A reg-prefetch + double-buffered LDS,
//              B direct-from-global fragswizzled (1 KB contiguous per wave)
// fc1_splitk:  c3 -> fp32 partials (6-way split-K, same pipeline)
// fc1_reduce:  partials -> feat (fp32 d_out) + fr (bf16 relu)
// cls1/cls2:   same template
// ---------------------------------------------------------------------------

typedef __attribute__((ext_vector_type(8))) short short8v;
typedef __attribute__((ext_vector_type(4))) float floatx4;

#define N_NODE 96
#define E_TOT  864
#define BATCH  8192ull

// ws layout, ushort elements
#define R0_OFF   0ull
#define R1_OFF   25165824ull
#define FR_OFF   50331648ull
#define R2_OFF   51380224ull
#define WT_OFF   52428800ull
#define W1N_OFF  (WT_OFF + 0)
#define W2N_OFF  (WT_OFF + 2048)
#define WC1_OFF  (WT_OFF + 4096)      // fragswizzled [4g][7ks][64][8]
#define WC2_OFF  (WT_OFF + 18432)     // [8g][10ks][64][8]
#define WC3_OFF  (WT_OFF + 59392)     // [16g][12ks][64][8]
#define WF1_OFF  (WT_OFF + 157696)    // [8g][96ks][64][8]
#define WL1_OFF  (WT_OFF + 550912)    // [8g][4ks][64][8]
#define WL2_OFF  (WT_OFF + 567296)    // [16g][4ks][64][8]
#define AH_OFF   (WT_OFF + 600064)    // dense Ahat bf16 [96][96]

__device__ __forceinline__ unsigned short f2b(float f) {
    unsigned int u = __builtin_bit_cast(unsigned int, f);
    u += 0x7fffu + ((u >> 16) & 1u);
    return (unsigned short)(u >> 16);
}
__device__ __forceinline__ float b2f(unsigned short h) {
    unsigned int u = ((unsigned int)h) << 16;
    return __builtin_bit_cast(float, u);
}

// ---------------------------------------------------------------------------
__global__ void prep_edges(const int* __restrict__ eidx, unsigned short* __restrict__ adense) {
    __shared__ int rowv[E_TOT];
    __shared__ int colv[E_TOT];
    __shared__ int degi[N_NODE];
    __shared__ float dinv[N_NODE];
    __shared__ float ad[96 * 96];
    const int tid = threadIdx.x;
    for (int e = tid; e < E_TOT; e += 256) {
        int r, c;
        if (e < 768) { r = eidx[e]; c = eidx[768 + e]; }
        else         { r = e - 768; c = r; }
        rowv[e] = r; colv[e] = c;
    }
    for (int n = tid; n < N_NODE; n += 256) degi[n] = 0;
    for (int i = tid; i < 9216; i += 256) ad[i] = 0.f;
    __syncthreads();
    for (int e = tid; e < E_TOT; e += 256) atomicAdd(&degi[rowv[e]], 1);
    __syncthreads();
    for (int n = tid; n < N_NODE; n += 256)
        dinv[n] = rsqrtf(fmaxf((float)degi[n], 1e-12f));
    __syncthreads();
    for (int e = tid; e < E_TOT; e += 256)
        atomicAdd(&ad[rowv[e] * 96 + colv[e]], dinv[rowv[e]] * dinv[colv[e]]);
    __syncthreads();
    for (int i = tid; i < 9216; i += 256) adense[i] = f2b(ad[i]);
}

// ---------------------------------------------------------------------------
// Fragment-swizzled B layout: group g (16 n-cols), kstep ks (32 k),
// lane = quad*16 + n16, j in [0,8): element = B[g*16+n16][ks*32+quad*8+j].
// ---------------------------------------------------------------------------
__global__ void prep_weights(const float* __restrict__ g1w, const float* __restrict__ g2w,
                             const float* __restrict__ w1, const float* __restrict__ w2,
                             const float* __restrict__ w3, const float* __restrict__ f1,
                             const float* __restrict__ l1, const float* __restrict__ l2,
                             unsigned short* __restrict__ wt) {
    long idx = (long)blockIdx.x * 256 + threadIdx.x;
    if (idx >= 600064) return;
    float v;
    if (idx < 2048) {                      // w1n[o][c] (gcn12, unswizzled)
        int o = idx >> 5, c = idx & 31;
        v = (c < 16) ? g1w[c * 64 + o] : 0.f;
    } else if (idx < 4096) {               // w2n[g][c] (gcn12, unswizzled)
        long j = idx - 2048; int g = j >> 6, c = j & 63;
        v = g2w[c * 32 + g];
    } else {
        long base, KS;
        int region;
        if      (idx < 18432)  { base = 4096;   KS = 7;  region = 0; }
        else if (idx < 59392)  { base = 18432;  KS = 10; region = 1; }
        else if (idx < 157696) { base = 59392;  KS = 12; region = 2; }
        else if (idx < 550912) { base = 157696; KS = 96; region = 3; }
        else if (idx < 567296) { base = 550912; KS = 4;  region = 4; }
        else                   { base = 567296; KS = 4;  region = 5; }
        long local = idx - base;
        long g  = local / (KS * 512);
        long rm = local % (KS * 512);
        long ks = rm / 512;
        int lane = (int)((rm % 512) / 8);
        int j    = (int)(rm % 8);
        int quad = lane >> 4, n16 = lane & 15;
        int n = (int)(g * 16 + n16);
        int k = (int)(ks * 32 + quad * 8 + j);
        switch (region) {
            case 0: { int t = k / 32,  c = k % 32;  v = w1[n * 224 + c * 7 + t]; } break;
            case 1: { int t = k / 64,  c = k % 64;  v = w2[n * 320 + c * 5 + t]; } break;
            case 2: { int t = k / 128, c = k % 128; v = w3[n * 384 + c * 3 + t]; } break;
            case 3: { int t = k / 256, o = k % 256; v = f1[(o * 12 + t) * 128 + n]; } break;
            case 4: v = l1[k * 128 + n]; break;
            default: v = (n < 210) ? l2[k * 210 + n] : 0.f; break;
        }
    }
    wt[idx] = f2b(v);
}

// ---------------------------------------------------------------------------
__launch_bounds__(256)
__global__ void trans16(const float* __restrict__ src, unsigned short* __restrict__ xt) {
    __shared__ __align__(16) float xs[8 * 1544];
    const int tid = threadIdx.x;
    const int b0 = blockIdx.x * 8;
    for (int u = tid; u < 3072; u += 256) {
        int bl = u / 384, j = u % 384;
        *(float4*)&xs[bl * 1544 + j * 4] =
            *(const float4*)&src[((size_t)(b0 + bl)) * 1536 + j * 4];
    }
    __syncthreads();
    for (int u = tid; u < 768; u += 256) {
        int n = u >> 3, bl = u & 7;
        const float* base = &xs[bl * 1544 + n];
        unsigned int d[8];
#pragma unroll
        for (int c2 = 0; c2 < 8; c2++)
            d[c2] = (unsigned int)f2b(base[(2 * c2) * 96]) |
                    ((unsigned int)f2b(base[(2 * c2 + 1) * 96]) << 16);
        unsigned int* o = (unsigned int*)(xt + ((size_t)n * BATCH + b0 + bl) * 16);
        *(uint4*)&o[0] = make_uint4(d[0], d[1], d[2], d[3]);
        *(uint4*)&o[4] = make_uint4(d[4], d[5], d[6], d[7]);
    }
}

// ---------------------------------------------------------------------------
template<int CH, bool RELU>
__launch_bounds__(256)
__global__ void agg_mm(const unsigned short* __restrict__ in,
                       const unsigned short* __restrict__ adense,
                       const float* __restrict__ bias,
                       unsigned short* __restrict__ outp) {
    const size_t NCOL = 8192ull * CH;
    __shared__ __align__(16) unsigned short Al[96 * 104];
    __shared__ __align__(16) unsigned short Bs[96 * 264];
    const int tid = threadIdx.x;
    const size_t c0 = (size_t)blockIdx.x * 256;
    const int w = tid >> 6, lane = tid & 63, quad = lane >> 4, m16 = lane & 15;

    for (int u = tid; u < 1152; u += 256) {
        int r = u / 12, q = u % 12;
        *(short8v*)&Al[r * 104 + q * 8] = *(const short8v*)&adense[r * 96 + q * 8];
    }
    for (int u = tid; u < 3072; u += 256) {
        int r = u >> 5, q = u & 31;
        *(uint4*)&Bs[r * 264 + q * 8] = *(const uint4*)&in[(size_t)r * NCOL + c0 + q * 8];
    }
    __syncthreads();

    floatx4 acc[6][4] = {};
    const int nb = w * 64;
#pragma unroll
    for (int kk = 0; kk < 96; kk += 32) {
        short8v bfr[4];
#pragma unroll
        for (int fn = 0; fn < 4; fn++) {
            const int col = nb + fn * 16 + m16;
#pragma unroll
            for (int j = 0; j < 8; j++)
                bfr[fn][j] = (short)Bs[(kk + quad * 8 + j) * 264 + col];
        }
#pragma unroll
        for (int fm = 0; fm < 6; fm++) {
            short8v afr = *(short8v*)&Al[(fm * 16 + m16) * 104 + kk + quad * 8];
#pragma unroll
            for (int fn = 0; fn < 4; fn++)
                acc[fm][fn] = __builtin_amdgcn_mfma_f32_16x16x32_bf16(afr, bfr[fn], acc[fm][fn], 0, 0, 0);
        }
    }

#pragma unroll
    for (int fm = 0; fm < 6; fm++) {
#pragma unroll
        for (int fn = 0; fn < 4; fn++) {
            const int col = nb + fn * 16 + m16;
            float bv = 0.f;
            if constexpr (RELU) bv = bias[col & (CH - 1)];
#pragma unroll
            for (int r = 0; r < 4; r++) {
                int node = fm * 16 + quad * 4 + r;
                float v = acc[fm][fn][r];
                if constexpr (RELU) v = fmaxf(v + bv, 0.f);
                outp[(size_t)node * NCOL + c0 + col] = f2b(v);
            }
        }
    }
}

// ---------------------------------------------------------------------------
__launch_bounds__(256)
__global__ void gcn12(const unsigned short* __restrict__ xa,
                      const unsigned short* __restrict__ w1n,
                      const unsigned short* __restrict__ w2n,
                      const float* __restrict__ b1, unsigned short* __restrict__ hw2) {
    __shared__ __align__(16) unsigned short As[128 * 40];
    __shared__ __align__(16) unsigned short B1s[64 * 40];
    __shared__ __align__(16) unsigned short H1s[128 * 72];
    __shared__ __align__(16) unsigned short B2s[32 * 72];
    const int tid = threadIdx.x;
    const size_t b0 = blockIdx.x * 128;
    const int l = blockIdx.z;
    const int w = tid >> 6, lane = tid & 63, quad = lane >> 4, m16 = lane & 15;

    short8v zz = {0, 0, 0, 0, 0, 0, 0, 0};
    for (int u = tid; u < 512; u += 256) {
        int r = u >> 2, cc = u & 3;
        *(short8v*)&As[r * 40 + cc * 8] = (cc < 2)
            ? *(const short8v*)&xa[((size_t)l * BATCH + b0 + r) * 16 + cc * 8]
            : zz;
    }
    for (int u = tid; u < 256; u += 256) {
        int r = u >> 2, cc = u & 3;
        *(short8v*)&B1s[r * 40 + cc * 8] = *(const short8v*)&w1n[r * 32 + cc * 8];
    }
    for (int u = tid; u < 256; u += 256) {
        int r = u >> 3, cc = u & 7;
        *(short8v*)&B2s[r * 72 + cc * 8] = *(const short8v*)&w2n[r * 64 + cc * 8];
    }
    __syncthreads();

    {
        const int wm = w >> 1, wq = w & 1;
        const int mbase = wm * 64, nbase = wq * 32;
        floatx4 acc[4][2] = {};
#pragma unroll
        for (int fn = 0; fn < 2; fn++) {
            short8v bfr = *(short8v*)&B1s[(nbase + fn * 16 + m16) * 40 + quad * 8];
#pragma unroll
            for (int fm = 0; fm < 4; fm++) {
                short8v afr = *(short8v*)&As[(mbase + fm * 16 + m16) * 40 + quad * 8];
                acc[fm][fn] = __builtin_amdgcn_mfma_f32_16x16x32_bf16(afr, bfr, acc[fm][fn], 0, 0, 0);
            }
        }
        float bv0 = b1[nbase + m16], bv1 = b1[nbase + 16 + m16];
#pragma unroll
        for (int fm = 0; fm < 4; fm++)
#pragma unroll
            for (int r = 0; r < 4; r++) {
                int row = mbase + fm * 16 + quad * 4 + r;
                H1s[row * 72 + nbase + m16]      = f2b(fmaxf(acc[fm][0][r] + bv0, 0.f));
                H1s[row * 72 + nbase + 16 + m16] = f2b(fmaxf(acc[fm][1][r] + bv1, 0.f));
            }
    }
    __syncthreads();

    {
        const int mb2 = w * 32;
        floatx4 acc[2][2] = {};
#pragma unroll
        for (int kk = 0; kk < 64; kk += 32)
#pragma unroll
            for (int fn = 0; fn < 2; fn++) {
                short8v bfr = *(short8v*)&B2s[(fn * 16 + m16) * 72 + kk + quad * 8];
#pragma unroll
                for (int fm = 0; fm < 2; fm++) {
                    short8v afr = *(short8v*)&H1s[(mb2 + fm * 16 + m16) * 72 + kk + quad * 8];
                    acc[fm][fn] = __builtin_amdgcn_mfma_f32_16x16x32_bf16(afr, bfr, acc[fm][fn], 0, 0, 0);
                }
            }
        unsigned short* Cs = As;
#pragma unroll
        for (int fm = 0; fm < 2; fm++)
#pragma unroll
            for (int r = 0; r < 4; r++) {
                int row = mb2 + fm * 16 + quad * 4 + r;
                Cs[row * 40 + m16]      = f2b(acc[fm][0][r]);
                Cs[row * 40 + 16 + m16] = f2b(acc[fm][1][r]);
            }
    }
    __syncthreads();
    for (int u = tid; u < 512; u += 256) {
        int r = u >> 2, cc = u & 3;
        *(short8v*)&hw2[((size_t)l * BATCH + b0 + r) * 32 + cc * 8] =
            *(short8v*)&As[r * 40 + cc * 8];
    }
}

// ---------------------------------------------------------------------------
// Pipelined hybrid slab GEMM: per stage, barrier -> issue next A-tile global
// loads (regs) -> MFMA on LDS buf[p] (hides load latency) -> write regs ->
// buf[p^1]. One barrier/stage; out-of-range taps zero-fill (exact).
// B direct-from-global fragswizzled. BM=WM*32, BN=FN*32, waves 2x2.
// MODE 0: bf16 out + bias + relu. MODE 4: fp32 out [210-stride], masked.
// ---------------------------------------------------------------------------
template<int WM, int FN, int NTAP, int CIN, int NOUT, int STRIDE, int PAD, int LIN, int BK, int MODE>
__launch_bounds__(256)
__global__ void gemm_slab(const unsigned short* __restrict__ in,
                          const unsigned short* __restrict__ wn,
                          const float* __restrict__ bias,
                          unsigned short* __restrict__ outb,
                          float* __restrict__ outf) {
    constexpr int BM  = WM * 32;
    constexpr int BN  = FN * 32;
    constexpr int BKP = BK + 8;
    constexpr int CPT = CIN / BK;
    constexpr int NC  = NTAP * CPT;
    constexpr int KS  = NTAP * CIN / 32;     // fragswizzle ksteps
    constexpr int NV  = BM * BK / 8 / 256;   // vec8 loads per thread per tile
    constexpr int RPV = 256 / (BK / 8);      // rows per 256-thread sweep
    constexpr int SZ1 = 2 * BM * BKP;
    constexpr int SZ2 = (MODE == 4) ? 16 : BM * (BN + 8);
    constexpr int POOL = SZ1 > SZ2 ? SZ1 : SZ2;
    __shared__ __align__(16) unsigned short pool[POOL];
    const int tid = threadIdx.x;
    const size_t b0 = blockIdx.x * BM;
    const int n0 = blockIdx.y * BN;
    const int l  = blockIdx.z;
    const int w = tid >> 6, lane = tid & 63, quad = lane >> 4, m16 = lane & 15;
    const int wm = w >> 1, wq = w & 1;
    const int mbase = wm * (WM * 16), nbase = wq * (FN * 16);
    const int gw = (n0 + nbase) >> 4;        // first 16-col weight group
    const int lr = tid / (BK / 8);           // staging row
    const int lc = tid % (BK / 8);           // staging vec8 col
    floatx4 acc[WM][FN] = {};
    const short8v zz8 = {0, 0, 0, 0, 0, 0, 0, 0};

    short8v pre[NV], nxt[NV];
    // prologue: load + write tile 0
    {
        int pos = STRIDE * l - PAD;
        if (pos >= 0 && pos < LIN) {
            const unsigned short* ag = in + ((size_t)pos * BATCH + b0) * CIN;
#pragma unroll
            for (int v = 0; v < NV; v++)
                pre[v] = *(const short8v*)&ag[(size_t)(lr + v * RPV) * CIN + lc * 8];
        } else {
#pragma unroll
            for (int v = 0; v < NV; v++) pre[v] = zz8;
        }
#pragma unroll
        for (int v = 0; v < NV; v++)
            *(short8v*)&pool[(lr + v * RPV) * BKP + lc * 8] = pre[v];
    }
    int p = 0;
#pragma unroll
    for (int ch = 0; ch < NC; ++ch) {
        __syncthreads();                      // buf[p] ready; no VMEM in flight
        if (ch + 1 < NC) {                    // issue next tile's global loads
            int t = (ch + 1) / CPT, inner = (ch + 1) % CPT;
            int pos = STRIDE * l + t - PAD;
            if (pos >= 0 && pos < LIN) {
                const unsigned short* ag = in + ((size_t)pos * BATCH + b0) * CIN + inner * BK;
#pragma unroll
                for (int v = 0; v < NV; v++)
                    nxt[v] = *(const short8v*)&ag[(size_t)(lr + v * RPV) * CIN + lc * 8];
            } else {
#pragma unroll
                for (int v = 0; v < NV; v++) nxt[v] = zz8;
            }
        }
        // MFMA on buf[p] — overlaps with the loads above
        const unsigned short* As = pool + p * BM * BKP;
        const int kbase = (ch / CPT) * CIN + (ch % CPT) * BK;
#pragma unroll
        for (int kk = 0; kk < BK; kk += 32) {
            const int ksG = (kbase + kk) >> 5;
            short8v bfr[FN];
#pragma unroll
            for (int fn = 0; fn < FN; fn++)
                bfr[fn] = *(const short8v*)&wn[(((size_t)(gw + fn) * KS + ksG) << 9) + lane * 8];
#pragma unroll
            for (int fm = 0; fm < WM; fm++) {
                short8v afr = *(const short8v*)&As[(mbase + fm * 16 + m16) * BKP + kk + quad * 8];
#pragma unroll
                for (int fn = 0; fn < FN; fn++)
                    acc[fm][fn] = __builtin_amdgcn_mfma_f32_16x16x32_bf16(afr, bfr[fn], acc[fm][fn], 0, 0, 0);
            }
        }
        if (ch + 1 < NC) {                    // write next into other buffer
            unsigned short* Ad = pool + (p ^ 1) * BM * BKP;
#pragma unroll
            for (int v = 0; v < NV; v++)
                *(short8v*)&Ad[(lr + v * RPV) * BKP + lc * 8] = nxt[v];
        }
        p ^= 1;
    }

    if constexpr (MODE == 4) {
#pragma unroll
        for (int fn = 0; fn < FN; fn++) {
            int cg = n0 + nbase + fn * 16 + m16;
            float bv = (cg < 210) ? bias[cg] : 0.f;
            if (cg < 210) {
#pragma unroll
                for (int fm = 0; fm < WM; fm++)
#pragma unroll
                    for (int r = 0; r < 4; r++) {
                        size_t row = b0 + mbase + fm * 16 + quad * 4 + r;
                        outf[row * 210 + cg] = acc[fm][fn][r] + bv;
                    }
            }
        }
    } else {
        float bv[FN];
#pragma unroll
        for (int fn = 0; fn < FN; fn++) bv[fn] = bias[n0 + nbase + fn * 16 + m16];
        __syncthreads();                      // all MFMA reads of pool done
        unsigned short* Cs = pool;
#pragma unroll
        for (int fm = 0; fm < WM; fm++)
#pragma unroll
            for (int r = 0; r < 4; r++) {
                int row = mbase + fm * 16 + quad * 4 + r;
#pragma unroll
                for (int fn = 0; fn < FN; fn++)
                    Cs[row * (BN + 8) + nbase + fn * 16 + m16] =
                        f2b(fmaxf(acc[fm][fn][r] + bv[fn], 0.f));
            }
        __syncthreads();
        for (int u = tid; u < BM * (BN / 8); u += 256) {
            int r = u / (BN / 8), cc = u % (BN / 8);
            *(short8v*)&outb[((size_t)l * BATCH + b0 + r) * NOUT + n0 + cc * 8] =
                *(short8v*)&Cs[r * (BN + 8) + cc * 8];
        }
    }
}

// ---------------------------------------------------------------------------
// fc1 split-K, pipelined: A (c3) reg-prefetch + dbuf LDS; B fragswizzled.
// grid (64, 1, 6); z handles taps {2z, 2z+1} (K=512, 8 stages of 64).
// ---------------------------------------------------------------------------
__launch_bounds__(256)
__global__ void fc1_splitk(const unsigned short* __restrict__ c3,
                           const unsigned short* __restrict__ wf1,
                           float* __restrict__ part) {
    __shared__ __align__(16) unsigned short pool[2 * 128 * 72];
    const int tid = threadIdx.x;
    const size_t b0 = blockIdx.x * 128;
    const int kg = blockIdx.z;
    const int w = tid >> 6, lane = tid & 63, quad = lane >> 4, m16 = lane & 15;
    const int wm = w >> 1, wq = w & 1;
    const int mbase = wm * 64, nbase = wq * 64;
    const int gw = nbase >> 4;
    const int lr = tid >> 3, lc = tid & 7;
    floatx4 acc[4][4] = {};
    short8v pre[4], nxt[4];

    // stage s: t = kg*2 + (s>>2), inner = s&3
    {
        const unsigned short* ag = c3 + ((size_t)(kg * 2) * BATCH + b0) * 256;
#pragma unroll
        for (int v = 0; v < 4; v++)
            pre[v] = *(const short8v*)&ag[(size_t)(lr + v * 32) * 256 + lc * 8];
#pragma unroll
        for (int v = 0; v < 4; v++)
            *(short8v*)&pool[(lr + v * 32) * 72 + lc * 8] = pre[v];
    }
    int p = 0;
#pragma unroll
    for (int s = 0; s < 8; ++s) {
        __syncthreads();
        if (s + 1 < 8) {
            int t = kg * 2 + ((s + 1) >> 2), inner = (s + 1) & 3;
            const unsigned short* ag = c3 + ((size_t)t * BATCH + b0) * 256 + inner * 64;
#pragma unroll
            for (int v = 0; v < 4; v++)
                nxt[v] = *(const short8v*)&ag[(size_t)(lr + v * 32) * 256 + lc * 8];
        }
        const unsigned short* As = pool + p * 128 * 72;
        const int kbase = (kg * 2 + (s >> 2)) * 256 + (s & 3) * 64;
#pragma unroll
        for (int kk = 0; kk < 64; kk += 32) {
            const int ksG = (kbase + kk) >> 5;    // KS = 96
            short8v bfr[4];
#pragma unroll
            for (int fn = 0; fn < 4; fn++)
                bfr[fn] = *(const short8v*)&wf1[(((size_t)(gw + fn) * 96 + ksG) << 9) + lane * 8];
#pragma unroll
            for (int fm = 0; fm < 4; fm++) {
                short8v afr = *(const short8v*)&As[(mbase + fm * 16 + m16) * 72 + kk + quad * 8];
#pragma unroll
                for (int fn = 0; fn < 4; fn++)
                    acc[fm][fn] = __builtin_amdgcn_mfma_f32_16x16x32_bf16(afr, bfr[fn], acc[fm][fn], 0, 0, 0);
            }
        }
        if (s + 1 < 8) {
            unsigned short* Ad = pool + (p ^ 1) * 128 * 72;
#pragma unroll
            for (int v = 0; v < 4; v++)
                *(short8v*)&Ad[(lr + v * 32) * 72 + lc * 8] = nxt[v];
        }
        p ^= 1;
    }
    float* pg = part + (size_t)kg * BATCH * 128;
#pragma unroll
    for (int fm = 0; fm < 4; fm++)
#pragma unroll
        for (int r = 0; r < 4; r++) {
            size_t row = b0 + mbase + fm * 16 + quad * 4 + r;
#pragma unroll
            for (int fn = 0; fn < 4; fn++)
                pg[row * 128 + nbase + fn * 16 + m16] = acc[fm][fn][r];
        }
}

// ---------------------------------------------------------------------------
__launch_bounds__(256)
__global__ void fc1_reduce(const float* __restrict__ part, const float* __restrict__ bias,
                           float* __restrict__ feat, unsigned short* __restrict__ fr) {
    const size_t idx = (size_t)blockIdx.x * 256 + threadIdx.x;
    const size_t row = idx >> 5;
    const int    c4  = (int)(idx & 31);
    float4 s = *(const float4*)&bias[c4 * 4];
#pragma unroll
    for (int z = 0; z < 6; z++) {
        float4 p = *(const float4*)&part[(z * BATCH + row) * 128 + c4 * 4];
        s.x += p.x; s.y += p.y; s.z += p.z; s.w += p.w;
    }
    *(float4*)&feat[row * 128 + c4 * 4] = s;
    unsigned int d0 = (unsigned int)f2b(fmaxf(s.x, 0.f)) |
                      ((unsigned int)f2b(fmaxf(s.y, 0.f)) << 16);
    unsigned int d1 = (unsigned int)f2b(fmaxf(s.z, 0.f)) |
                      ((unsigned int)f2b(fmaxf(s.w, 0.f)) << 16);
    *(uint2*)&fr[row * 128 + c4 * 4] = make_uint2(d0, d1);
}

// ---------------------------------------------------------------------------
extern "C" void kernel_launch(void* const* d_in, const int* in_sizes, int n_in,
                              void* d_out, int out_size, void* d_ws, size_t ws_size,
                              hipStream_t stream) {
    const float* src  = (const float*)d_in[0];
    const int*   eidx = (const int*)  d_in[1];
    const float* g1w  = (const float*)d_in[2];
    const float* g1b  = (const float*)d_in[3];
    const float* g2w  = (const float*)d_in[4];
    const float* g2b  = (const float*)d_in[5];
    const float* cv1w = (const float*)d_in[6];
    const float* cv1b = (const float*)d_in[7];
    const float* cv2w = (const float*)d_in[8];
    const float* cv2b = (const float*)d_in[9];
    const float* cv3w = (const float*)d_in[10];
    const float* cv3b = (const float*)d_in[11];
    const float* fc1w = (const float*)d_in[12];
    const float* fc1b = (const float*)d_in[13];
    const float* cl1w = (const float*)d_in[14];
    const float* cl1b = (const float*)d_in[15];
    const float* cl2w = (const float*)d_in[16];
    const float* cl2b = (const float*)d_in[17];

    unsigned short* ws16 = (unsigned short*)d_ws;
    float* wsF = (float*)d_ws;
    float* out = (float*)d_out;

    unsigned short* xt  = ws16 + R1_OFF;
    unsigned short* xa  = ws16 + R0_OFF;
    unsigned short* hw2 = ws16 + R1_OFF;
    unsigned short* h2  = ws16 + R0_OFF;
    unsigned short* c1  = ws16 + R1_OFF;
    unsigned short* c2  = ws16 + R0_OFF;
    unsigned short* c3  = ws16 + R1_OFF;
    float*          part = wsF;              // aliases dead c2 (R0)
    unsigned short* fr  = ws16 + FR_OFF;
    unsigned short* r2  = ws16 + R2_OFF;
    unsigned short* w1n = ws16 + W1N_OFF;
    unsigned short* w2n = ws16 + W2N_OFF;
    unsigned short* wc1 = ws16 + WC1_OFF;
    unsigned short* wc2 = ws16 + WC2_OFF;
    unsigned short* wc3 = ws16 + WC3_OFF;
    unsigned short* wf1 = ws16 + WF1_OFF;
    unsigned short* wl1 = ws16 + WL1_OFF;
    unsigned short* wl2 = ws16 + WL2_OFF;
    unsigned short* ah  = ws16 + AH_OFF;

    float* feat_out = out + 8192ull * 210ull;

    prep_edges<<<1, 256, 0, stream>>>(eidx, ah);
    prep_weights<<<2345, 256, 0, stream>>>(g1w, g2w, cv1w, cv2w, cv3w, fc1w, cl1w, cl2w,
                                           ws16 + WT_OFF);
    trans16<<<1024, 256, 0, stream>>>(src, xt);
    agg_mm<16, false><<<512, 256, 0, stream>>>(xt, ah, nullptr, xa);
    gcn12<<<dim3(64, 1, 96), 256, 0, stream>>>(xa, w1n, w2n, g1b, hw2);
    agg_mm<32, true><<<1024, 256, 0, stream>>>(hw2, ah, g2b, h2);
    // conv1: BM=256, BN=64, BK=32, 7 pipelined stages
    gemm_slab<8, 2, 7, 32, 64, 2, 3, 96, 32, 0>
        <<<dim3(32, 1, 48), 256, 0, stream>>>(h2, wc1, cv1b, c1, nullptr);
    // conv2: BM=128, BN=128, BK=64, 10 stages
    gemm_slab<4, 4, 5, 64, 128, 2, 2, 48, 64, 0>
        <<<dim3(64, 1, 24), 256, 0, stream>>>(c1, wc2, cv2b, c2, nullptr);
    // conv3: BM=128, BN=128 (y=2), BK=64, 6 stages
    gemm_slab<4, 4, 3, 128, 256, 2, 1, 24, 64, 0>
        <<<dim3(64, 2, 12), 256, 0, stream>>>(c2, wc3, cv3b, c3, nullptr);
    fc1_splitk<<<dim3(64, 1, 6), 256, 0, stream>>>(c3, wf1, part);
    fc1_reduce<<<1024, 256, 0, stream>>>(part, fc1b, feat_out, fr);
    gemm_slab<2, 2, 1, 128, 128, 1, 0, 1, 64, 0>
        <<<dim3(128, 2, 1), 256, 0, stream>>>(fr, wl1, cl1b, r2, nullptr);
    gemm_slab<2, 2, 1, 128, 256, 1, 0, 1, 64, 4>
        <<<dim3(128, 4, 1), 256, 0, stream>>>(r2, wl2, cl2b, nullptr, out);
}